// Round 7
// baseline (136.578 us; speedup 1.0000x reference)
//
#include <hip/hip_runtime.h>
#include <hip/hip_bf16.h>
#include <stdint.h>

#define NPTS   131072
#define NANCH  1024
#define GRID   25
#define NCELL  (GRID*GRID)
#define CINV   0.25f
#define MAXP   512
#define MINP   4
#define IDXCAP 1024   // >= max possible inside-count (max E ~472, sigma ~22)
#define HB     128    // binning blocks (<=256 CUs -> co-resident, spin-release safe)
#define PPB    (NPTS/HB)   // 1024 points per block

typedef __attribute__((ext_vector_type(8))) short bf16x8;
typedef __attribute__((ext_vector_type(4))) float f32x4;

__device__ __forceinline__ int cell_of(float px, float py) {
    int cx = (int)(px * CINV); cx = cx < 0 ? 0 : (cx > GRID-1 ? GRID-1 : cx);
    int cy = (int)(py * CINV); cy = cy < 0 ? 0 : (cy > GRID-1 ? GRID-1 : cy);
    return cy * GRID + cx;
}

__device__ __forceinline__ unsigned short f2bf(float f) {   // RNE
    union { float f; uint32_t u; } v; v.f = f;
    return (unsigned short)((v.u + 0x7fff + ((v.u >> 16) & 1)) >> 16);
}

// ---------------- fused binning: hist -> last-block scan -> scatter ----------------
// One kernel, 128 blocks. Points + cell + within-(block,cell) rank live in registers
// across the internal release barrier. sync_ctr/rel_flag are memset to 0 beforehand.

__global__ __launch_bounds__(256) void k_bin(const float* __restrict__ pts,
                                             const float* __restrict__ W2,
                                             int* __restrict__ blockhist,
                                             int* __restrict__ blockpre,
                                             int* __restrict__ cstart,
                                             unsigned short* __restrict__ w2tg,
                                             float4* __restrict__ binned,
                                             int* __restrict__ sync_ctr,
                                             int* __restrict__ rel_flag) {
    __shared__ int lh[NCELL];
    __shared__ int tsum[256];
    __shared__ int s_last;
    const int b = blockIdx.x, tid = threadIdx.x;

    for (int i = tid; i < NCELL; i += 256) lh[i] = 0;
    __syncthreads();

    float px[4], py[4], pz[4]; int pc[4], pr[4];
    const int base = b * PPB;
    #pragma unroll
    for (int k = 0; k < 4; k++) {
        int i = base + k*256 + tid;
        px[k] = pts[3*i]; py[k] = pts[3*i+1]; pz[k] = pts[3*i+2];
        pc[k] = cell_of(px[k], py[k]);
        pr[k] = atomicAdd(&lh[pc[k]], 1);        // LDS atomic: rank within (block,cell)
    }
    __syncthreads();
    for (int i = tid; i < NCELL; i += 256) blockhist[b*NCELL + i] = lh[i];

    if (b == 0) {                                 // W2^T bf16 prep, overlaps the scan
        int col = tid >> 1, ks = (tid & 1) * 32;
        #pragma unroll
        for (int kk = 0; kk < 32; kk += 2) {
            int k2 = ks + kk;
            uint32_t pk = (uint32_t)f2bf(W2[k2*128 + col])
                        | ((uint32_t)f2bf(W2[(k2+1)*128 + col]) << 16);
            *(uint32_t*)&w2tg[col*64 + k2] = pk;
        }
    }

    __threadfence();
    if (tid == 0) s_last = (atomicAdd(sync_ctr, 1) == HB - 1);
    __syncthreads();

    if (s_last) {
        // ---- scan: per-cell prefix over blocks (strided cells per thread) ----
        #pragma unroll
        for (int u = 0; u < 3; u++) {
            int c = tid + u*256;
            if (c < NCELL) {
                int a2 = 0;
                #pragma unroll 8
                for (int bb = 0; bb < HB; bb++) {
                    int v = blockhist[bb*NCELL + c];
                    blockpre[bb*NCELL + c] = a2;
                    a2 += v;
                }
                lh[c] = a2;                       // overwrite hist with cell totals
            }
        }
        __syncthreads();
        // ---- exclusive scan over 625 cell totals: 3 consecutive cells/thread ----
        int c0 = 3*tid;
        int v0 = (c0   < NCELL) ? lh[c0]   : 0;
        int v1 = (c0+1 < NCELL) ? lh[c0+1] : 0;
        int v2 = (c0+2 < NCELL) ? lh[c0+2] : 0;
        tsum[tid] = v0 + v1 + v2;
        __syncthreads();
        for (int off = 1; off < 256; off <<= 1) {
            int x = (tid >= off) ? tsum[tid - off] : 0;
            __syncthreads();
            tsum[tid] += x;
            __syncthreads();
        }
        int excl = tid ? tsum[tid-1] : 0;
        if (c0   < NCELL) cstart[c0]   = excl;
        if (c0+1 < NCELL) cstart[c0+1] = excl + v0;
        if (c0+2 < NCELL) cstart[c0+2] = excl + v0 + v1;
        if (tid == 255) cstart[NCELL] = tsum[255];   // total
        __threadfence();
        if (tid == 0) atomicExch(rel_flag, 1);
    } else {
        if (tid == 0) {
            while (atomicAdd(rel_flag, 0) == 0) { __builtin_amdgcn_s_sleep(2); }
        }
        __syncthreads();
        __threadfence();
    }

    // ---- scatter (deterministic positions, no atomics) ----
    #pragma unroll
    for (int k = 0; k < 4; k++) {
        int c = pc[k];
        int pos = cstart[c] + blockpre[b*NCELL + c] + pr[k];
        binned[pos] = make_float4(px[k], py[k], pz[k],
                                  __int_as_float(base + k*256 + tid));
    }
}

// ---------------- main kernel: one block (4 waves) per anchor ----------------

__launch_bounds__(256, 4)
__global__ void k_main(const float* __restrict__ pts,    // original order (fallback reload)
                       const float* __restrict__ anch,
                       const float* __restrict__ W1, const float* __restrict__ b1,
                       const float* __restrict__ b2,
                       const float* __restrict__ Wc, const float* __restrict__ bc,
                       const float* __restrict__ Wr, const float* __restrict__ br,
                       const unsigned short* __restrict__ w2tg,
                       const float4* __restrict__ binned,
                       const int* __restrict__ cstart,
                       float* __restrict__ out) {
    __shared__ float spx[MAXP], spy[MAXP], spz[MAXP];   // gathered rel coords (6KB)
    __shared__ int   sidx[IDXCAP];                      // orig indices (4KB)
    __shared__ unsigned short h1b[64*64];               // h1 chunk bf16, swizzled (8KB)
    __shared__ float w1s[3][64];
    __shared__ float b1s[64];
    __shared__ float gmax2[128];
    __shared__ int   s_cnt;

    const int a    = blockIdx.x;
    const int tid  = threadIdx.x;
    const int lane = tid & 63;
    const int wv   = tid >> 6;
    const int l15  = lane & 15;
    const int kb   = (lane >> 4) * 8;

    const float ax = anch[6*a],   ay = anch[6*a+1];
    const float w  = anch[6*a+3], l  = anch[6*a+4], hh = anch[6*a+5];
    const float hw = w * 0.5f, hl = l * 0.5f;
    const float x0 = ax - hw, x1 = ax + hw, y0 = ay - hl, y1 = ay + hl;

    // B-fragments (W2^T) straight from precomputed global, reused all chunks.
    bf16x8 b00, b01, b10, b11;
    {
        const int c0 = wv*16 + l15, c1 = c0 + 64;
        b00 = *(const bf16x8*)&w2tg[c0*64 + kb];
        b01 = *(const bf16x8*)&w2tg[c0*64 + 32 + kb];
        b10 = *(const bf16x8*)&w2tg[c1*64 + kb];
        b11 = *(const bf16x8*)&w2tg[c1*64 + 32 + kb];
    }

    if (tid == 0) s_cnt = 0;
    if (tid < 64) {
        w1s[0][tid] = W1[tid]; w1s[1][tid] = W1[64+tid]; w1s[2][tid] = W1[128+tid];
        b1s[tid] = b1[tid];
    }
    __syncthreads();

    // ---- phase A: gather inside points (ballot-compacted, unordered) ----
    int cx0 = (int)floorf(x0 * CINV); if (cx0 < 0) cx0 = 0;
    int cx1 = (int)floorf(x1 * CINV); if (cx1 > GRID-1) cx1 = GRID-1;
    int cy0 = (int)floorf(y0 * CINV); if (cy0 < 0) cy0 = 0;
    int cy1 = (int)floorf(y1 * CINV); if (cy1 > GRID-1) cy1 = GRID-1;

    for (int cy = cy0; cy <= cy1; cy++)
        for (int cx = cx0; cx <= cx1; cx++) {
            int c = cy * GRID + cx;
            int p0 = cstart[c], p1 = cstart[c+1];
            for (int base = p0; base < p1; base += 256) {
                int i = base + tid;
                bool ins = false;
                float4 P;
                if (i < p1) {
                    P = binned[i];
                    ins = (P.x >= x0) & (P.x <= x1) & (P.y >= y0) & (P.y <= y1)
                        & (P.z >= 0.f) & (P.z <= hh);
                }
                unsigned long long m = __ballot(ins);
                int wbase;
                if (lane == 0) wbase = atomicAdd(&s_cnt, __popcll(m));
                wbase = __shfl(wbase, 0);
                if (ins) {
                    int pos = wbase + __popcll(m & ((1ull << lane) - 1ull));
                    if (pos < MAXP)   { spx[pos] = P.x - ax; spy[pos] = P.y - ay; spz[pos] = P.z; }
                    if (pos < IDXCAP) sidx[pos] = __float_as_int(P.w);
                }
            }
        }
    __syncthreads();
    const int cnt = s_cnt;

    if (cnt < MINP) {               // zeroed row (valid==0), covers cnt==0
        if (tid < 5) out[5*a + tid] = 0.f;
        return;
    }

    // ---- rare fallback: cnt>512 needs "first 512 by original index" ----
    if (cnt > MAXP) {
        for (int i = cnt + tid; i < IDXCAP; i += 256) sidx[i] = 0x7fffffff;
        __syncthreads();
        for (int k = 2; k <= IDXCAP; k <<= 1) {
            for (int j = k >> 1; j > 0; j >>= 1) {
                #pragma unroll
                for (int e = 0; e < IDXCAP/256; e++) {
                    int i = tid + e*256;
                    int partner = i ^ j;
                    if (partner > i) {
                        int va = sidx[i], vb = sidx[partner];
                        bool up = ((i & k) == 0);
                        if ((va > vb) == up) { sidx[i] = vb; sidx[partner] = va; }
                    }
                }
                __syncthreads();
            }
        }
        for (int i = tid; i < MAXP; i += 256) {
            int idx = sidx[i];
            spx[i] = pts[3*idx]   - ax;
            spy[i] = pts[3*idx+1] - ay;
            spz[i] = pts[3*idx+2];
        }
        __syncthreads();
    }

    // ---- pad to multiple of 64 with copies of point 0 (max-invariant) ----
    const int gathered = cnt < MAXP ? cnt : MAXP;
    const int padded   = (gathered + 63) & ~63;
    for (int i = gathered + tid; i < padded; i += 256) {
        spx[i] = spx[0]; spy[i] = spy[0]; spz[i] = spz[0];
    }
    __syncthreads();

    // ---- layer-1 weight registers: this thread covers dims 4*dg..4*dg+3 ----
    const int dg    = tid & 15;               // dim group
    const int rowst = (tid >> 4) & 15;        // row strip: rows rowst + 16p
    float wxr[4], wyr[4], wzr[4], bbr[4];
    #pragma unroll
    for (int j = 0; j < 4; j++) {
        int d = 4*dg + j;
        wxr[j] = w1s[0][d]; wyr[j] = w1s[1][d]; wzr[j] = w1s[2][d]; bbr[j] = b1s[d];
    }

    // ---- phase B: layer1 (fp32->bf16, b64 writes) + MFMA layer2, 64-pt chunks ----
    float gm0 = -INFINITY, gm1 = -INFINITY;   // raw max (bias+relu deferred)

    for (int pb = 0; pb < padded; pb += 64) {
        // layer 1: h1[64][64] bf16 into swizzled LDS; 4 dims x 4 rows per thread
        #pragma unroll
        for (int p = 0; p < 4; p++) {
            int row = p*16 + rowst;
            float qx = spx[pb+row], qy = spy[pb+row], qz = spz[pb+row];
            float v0 = fmaf(qz, wzr[0], fmaf(qy, wyr[0], fmaf(qx, wxr[0], bbr[0])));
            float v1 = fmaf(qz, wzr[1], fmaf(qy, wyr[1], fmaf(qx, wxr[1], bbr[1])));
            float v2 = fmaf(qz, wzr[2], fmaf(qy, wyr[2], fmaf(qx, wxr[2], bbr[2])));
            float v3 = fmaf(qz, wzr[3], fmaf(qy, wyr[3], fmaf(qx, wxr[3], bbr[3])));
            v0 = fmaxf(v0, 0.f); v1 = fmaxf(v1, 0.f);
            v2 = fmaxf(v2, 0.f); v3 = fmaxf(v3, 0.f);
            __hip_bfloat162 lo = __float22bfloat162_rn(float2{v0, v1});
            __hip_bfloat162 hi = __float22bfloat162_rn(float2{v2, v3});
            uint2 val;
            val.x = *(uint32_t*)&lo;
            val.y = *(uint32_t*)&hi;
            int idx = (row*64 + 4*dg) ^ ((row & 7) << 3);
            *(uint2*)&h1b[idx] = val;            // ds_write_b64
        }
        __syncthreads();

        #pragma unroll
        for (int mt = 0; mt < 4; mt++) {
            int r = mt*16 + l15;
            int ai0 = (r*64 +      kb) ^ ((r & 7) << 3);
            int ai1 = (r*64 + 32 + kb) ^ ((r & 7) << 3);
            bf16x8 a0 = *(const bf16x8*)&h1b[ai0];
            bf16x8 a1 = *(const bf16x8*)&h1b[ai1];
            f32x4 z = {0.f, 0.f, 0.f, 0.f};
            f32x4 c;
            c = __builtin_amdgcn_mfma_f32_16x16x32_bf16(a0, b00, z, 0, 0, 0);
            c = __builtin_amdgcn_mfma_f32_16x16x32_bf16(a1, b01, c, 0, 0, 0);
            gm0 = fmaxf(gm0, fmaxf(fmaxf(c[0], c[1]), fmaxf(c[2], c[3])));
            c = __builtin_amdgcn_mfma_f32_16x16x32_bf16(a0, b10, z, 0, 0, 0);
            c = __builtin_amdgcn_mfma_f32_16x16x32_bf16(a1, b11, c, 0, 0, 0);
            gm1 = fmaxf(gm1, fmaxf(fmaxf(c[0], c[1]), fmaxf(c[2], c[3])));
        }
        __syncthreads();   // before next chunk overwrites h1b
    }

    // reduce across the 4 row-groups (lanes L, L^16, L^32, L^48 share col)
    gm0 = fmaxf(gm0, __shfl_xor(gm0, 16)); gm0 = fmaxf(gm0, __shfl_xor(gm0, 32));
    gm1 = fmaxf(gm1, __shfl_xor(gm1, 16)); gm1 = fmaxf(gm1, __shfl_xor(gm1, 32));
    if (lane < 16) {
        gmax2[wv*16     + lane] = gm0;
        gmax2[(wv+4)*16 + lane] = gm1;
    }
    __syncthreads();
    if (tid < 128) gmax2[tid] = fmaxf(gmax2[tid] + b2[tid], 0.f);   // bias + relu
    __syncthreads();

    // final heads: out = [g@Wc+bc, g@Wr+br]
    if (tid < 5) {
        const float* Wv; float bias; int stride;
        if (tid == 0) { Wv = Wc;            bias = bc[0];      stride = 1; }
        else          { Wv = Wr + (tid-1);  bias = br[tid-1];  stride = 4; }
        float acc = bias;
        for (int i = 0; i < 128; i++) acc = fmaf(gmax2[i], Wv[i*stride], acc);
        out[5*a + tid] = acc;
    }
}

// ---------------- launch ----------------

extern "C" void kernel_launch(void* const* d_in, const int* in_sizes, int n_in,
                              void* d_out, int out_size, void* d_ws, size_t ws_size,
                              hipStream_t stream) {
    const float* pts  = (const float*)d_in[0];
    const float* anch = (const float*)d_in[1];
    const float* W1   = (const float*)d_in[2];
    const float* b1   = (const float*)d_in[3];
    const float* W2   = (const float*)d_in[4];
    const float* b2   = (const float*)d_in[5];
    const float* Wc   = (const float*)d_in[6];
    const float* bc   = (const float*)d_in[7];
    const float* Wr   = (const float*)d_in[8];
    const float* br   = (const float*)d_in[9];
    float* out = (float*)d_out;

    char* ws = (char*)d_ws;
    float4*         binned    = (float4*)ws;                        // 2 MB @0
    int*            blockhist = (int*)(ws + (size_t)NPTS*16);       // 320 KB
    int*            blockpre  = blockhist + HB*NCELL;               // 320 KB
    int*            cstart    = blockpre  + HB*NCELL;               // 626 ints
    unsigned short* w2tg      = (unsigned short*)(ws + 2739712);    // 16 KB (16B aligned)
    int*            syncp     = (int*)(ws + 2756096);               // [0]=ctr [1]=flag

    hipMemsetAsync(syncp, 0, 16, stream);
    k_bin  <<<HB, 256, 0, stream>>>(pts, W2, blockhist, blockpre, cstart,
                                    w2tg, binned, syncp, syncp + 1);
    k_main <<<NANCH, 256, 0, stream>>>(pts, anch, W1, b1, b2, Wc, bc, Wr, br,
                                       w2tg, binned, cstart, out);
}

// Round 8
// 99.568 us; speedup vs baseline: 1.3717x; 1.3717x over previous
//
#include <hip/hip_runtime.h>
#include <hip/hip_bf16.h>
#include <stdint.h>

#define NPTS   131072
#define NANCH  1024
#define GRID   25
#define NCELL  (GRID*GRID)
#define CINV   0.25f
#define MAXP   512
#define MINP   4
#define IDXCAP 1024   // >= max possible inside-count (max E ~472, sigma ~22)
#define HB     128    // binning blocks
#define PPB    (NPTS/HB)   // 1024 points per block
#define CAP    384    // per-cell capacity (mean 210, sigma 14.5 -> +12 sigma)

typedef __attribute__((ext_vector_type(8))) short bf16x8;
typedef __attribute__((ext_vector_type(4))) float f32x4;

__device__ __forceinline__ int cell_of(float px, float py) {
    int cx = (int)(px * CINV); cx = cx < 0 ? 0 : (cx > GRID-1 ? GRID-1 : cx);
    int cy = (int)(py * CINV); cy = cy < 0 ? 0 : (cy > GRID-1 ? GRID-1 : cy);
    return cy * GRID + cx;
}

__device__ __forceinline__ unsigned short f2bf(float f) {   // RNE
    union { float f; uint32_t u; } v; v.f = f;
    return (unsigned short)((v.u + 0x7fff + ((v.u >> 16) & 1)) >> 16);
}

// ---------------- binning: one kernel, fixed-capacity cell rows ----------------
// Per block: LDS hist (per-point rank in regs) -> 1 global atomicAdd per
// (block,cell) to reserve a range -> direct scatter. No scan, no second pass.
// gcount must be zeroed beforehand (tiny memset).

__global__ __launch_bounds__(256) void k_bin(const float* __restrict__ pts,
                                             const float* __restrict__ W2,
                                             int* __restrict__ gcount,
                                             float4* __restrict__ binned,
                                             unsigned short* __restrict__ w2tg) {
    __shared__ int lh[NCELL];
    __shared__ int lbase[NCELL];
    const int b = blockIdx.x, tid = threadIdx.x;

    for (int i = tid; i < NCELL; i += 256) lh[i] = 0;
    __syncthreads();

    float px[4], py[4], pz[4]; int pc[4], pr[4];
    const int base = b * PPB;
    #pragma unroll
    for (int k = 0; k < 4; k++) {
        int i = base + k*256 + tid;
        px[k] = pts[3*i]; py[k] = pts[3*i+1]; pz[k] = pts[3*i+2];
        pc[k] = cell_of(px[k], py[k]);
        pr[k] = atomicAdd(&lh[pc[k]], 1);      // LDS atomic: rank within (block,cell)
    }
    __syncthreads();

    // reserve [lbase, lbase+lh) in each cell's row (distinct addresses per lane)
    for (int i = tid; i < NCELL; i += 256) {
        int n = lh[i];
        lbase[i] = n ? atomicAdd(&gcount[i], n) : 0;
    }
    __syncthreads();

    #pragma unroll
    for (int k = 0; k < 4; k++) {
        int c = pc[k];
        int r = lbase[c] + pr[k];
        if (r < CAP)                            // +12 sigma margin; guard vs UB
            binned[c*CAP + r] = make_float4(px[k], py[k], pz[k],
                                            __int_as_float(base + k*256 + tid));
    }

    if (b == 0) {                               // W2^T bf16 [128 col][64 k] prep
        int col = tid >> 1, ks = (tid & 1) * 32;
        #pragma unroll
        for (int kk = 0; kk < 32; kk += 2) {
            int k2 = ks + kk;
            uint32_t pk = (uint32_t)f2bf(W2[k2*128 + col])
                        | ((uint32_t)f2bf(W2[(k2+1)*128 + col]) << 16);
            *(uint32_t*)&w2tg[col*64 + k2] = pk;
        }
    }
}

// ---------------- main kernel: one block (4 waves) per anchor ----------------

__launch_bounds__(256, 4)
__global__ void k_main(const float* __restrict__ pts,    // original order (fallback reload)
                       const float* __restrict__ anch,
                       const float* __restrict__ W1, const float* __restrict__ b1,
                       const float* __restrict__ b2,
                       const float* __restrict__ Wc, const float* __restrict__ bc,
                       const float* __restrict__ Wr, const float* __restrict__ br,
                       const unsigned short* __restrict__ w2tg,
                       const float4* __restrict__ binned,
                       const int* __restrict__ gcount,
                       float* __restrict__ out) {
    __shared__ float spx[MAXP], spy[MAXP], spz[MAXP];   // gathered rel coords (6KB)
    __shared__ int   sidx[IDXCAP];                      // orig indices (4KB)
    __shared__ unsigned short h1b[64*64];               // h1 chunk bf16, swizzled (8KB)
    __shared__ float w1s[3][64];
    __shared__ float b1s[64];
    __shared__ float gmax2[128];
    __shared__ int   s_cnt;

    const int a    = blockIdx.x;
    const int tid  = threadIdx.x;
    const int lane = tid & 63;
    const int wv   = tid >> 6;
    const int l15  = lane & 15;
    const int kb   = (lane >> 4) * 8;

    const float ax = anch[6*a],   ay = anch[6*a+1];
    const float w  = anch[6*a+3], l  = anch[6*a+4], hh = anch[6*a+5];
    const float hw = w * 0.5f, hl = l * 0.5f;
    const float x0 = ax - hw, x1 = ax + hw, y0 = ay - hl, y1 = ay + hl;

    // B-fragments (W2^T) straight from precomputed global, reused all chunks.
    bf16x8 b00, b01, b10, b11;
    {
        const int c0 = wv*16 + l15, c1 = c0 + 64;
        b00 = *(const bf16x8*)&w2tg[c0*64 + kb];
        b01 = *(const bf16x8*)&w2tg[c0*64 + 32 + kb];
        b10 = *(const bf16x8*)&w2tg[c1*64 + kb];
        b11 = *(const bf16x8*)&w2tg[c1*64 + 32 + kb];
    }

    if (tid == 0) s_cnt = 0;
    if (tid < 64) {
        w1s[0][tid] = W1[tid]; w1s[1][tid] = W1[64+tid]; w1s[2][tid] = W1[128+tid];
        b1s[tid] = b1[tid];
    }
    __syncthreads();

    // ---- phase A: gather inside points (ballot-compacted, unordered) ----
    int cx0 = (int)floorf(x0 * CINV); if (cx0 < 0) cx0 = 0;
    int cx1 = (int)floorf(x1 * CINV); if (cx1 > GRID-1) cx1 = GRID-1;
    int cy0 = (int)floorf(y0 * CINV); if (cy0 < 0) cy0 = 0;
    int cy1 = (int)floorf(y1 * CINV); if (cy1 > GRID-1) cy1 = GRID-1;

    for (int cy = cy0; cy <= cy1; cy++)
        for (int cx = cx0; cx <= cx1; cx++) {
            int c = cy * GRID + cx;
            int n = gcount[c]; n = n < CAP ? n : CAP;
            int p0 = c*CAP, p1 = p0 + n;
            for (int base = p0; base < p1; base += 256) {
                int i = base + tid;
                bool ins = false;
                float4 P;
                if (i < p1) {
                    P = binned[i];
                    ins = (P.x >= x0) & (P.x <= x1) & (P.y >= y0) & (P.y <= y1)
                        & (P.z >= 0.f) & (P.z <= hh);
                }
                unsigned long long m = __ballot(ins);
                int wbase;
                if (lane == 0) wbase = atomicAdd(&s_cnt, __popcll(m));
                wbase = __shfl(wbase, 0);
                if (ins) {
                    int pos = wbase + __popcll(m & ((1ull << lane) - 1ull));
                    if (pos < MAXP)   { spx[pos] = P.x - ax; spy[pos] = P.y - ay; spz[pos] = P.z; }
                    if (pos < IDXCAP) sidx[pos] = __float_as_int(P.w);
                }
            }
        }
    __syncthreads();
    const int cnt = s_cnt;

    if (cnt < MINP) {               // zeroed row (valid==0), covers cnt==0
        if (tid < 5) out[5*a + tid] = 0.f;
        return;
    }

    // ---- rare fallback: cnt>512 needs "first 512 by original index" ----
    if (cnt > MAXP) {
        for (int i = cnt + tid; i < IDXCAP; i += 256) sidx[i] = 0x7fffffff;
        __syncthreads();
        for (int k = 2; k <= IDXCAP; k <<= 1) {
            for (int j = k >> 1; j > 0; j >>= 1) {
                #pragma unroll
                for (int e = 0; e < IDXCAP/256; e++) {
                    int i = tid + e*256;
                    int partner = i ^ j;
                    if (partner > i) {
                        int va = sidx[i], vb = sidx[partner];
                        bool up = ((i & k) == 0);
                        if ((va > vb) == up) { sidx[i] = vb; sidx[partner] = va; }
                    }
                }
                __syncthreads();
            }
        }
        for (int i = tid; i < MAXP; i += 256) {
            int idx = sidx[i];
            spx[i] = pts[3*idx]   - ax;
            spy[i] = pts[3*idx+1] - ay;
            spz[i] = pts[3*idx+2];
        }
        __syncthreads();
    }

    // ---- pad to multiple of 64 with copies of point 0 (max-invariant) ----
    const int gathered = cnt < MAXP ? cnt : MAXP;
    const int padded   = (gathered + 63) & ~63;
    for (int i = gathered + tid; i < padded; i += 256) {
        spx[i] = spx[0]; spy[i] = spy[0]; spz[i] = spz[0];
    }
    __syncthreads();

    // ---- layer-1 weight registers: this thread covers dims 4*dg..4*dg+3 ----
    const int dg    = tid & 15;               // dim group
    const int rowst = (tid >> 4) & 15;        // row strip: rows rowst + 16p
    float wxr[4], wyr[4], wzr[4], bbr[4];
    #pragma unroll
    for (int j = 0; j < 4; j++) {
        int d = 4*dg + j;
        wxr[j] = w1s[0][d]; wyr[j] = w1s[1][d]; wzr[j] = w1s[2][d]; bbr[j] = b1s[d];
    }

    // ---- phase B: layer1 (fp32->bf16, b64 writes) + MFMA layer2, 64-pt chunks ----
    float gm0 = -INFINITY, gm1 = -INFINITY;   // raw max (bias+relu deferred)

    for (int pb = 0; pb < padded; pb += 64) {
        // layer 1: h1[64][64] bf16 into swizzled LDS; 4 dims x 4 rows per thread
        #pragma unroll
        for (int p = 0; p < 4; p++) {
            int row = p*16 + rowst;
            float qx = spx[pb+row], qy = spy[pb+row], qz = spz[pb+row];
            float v0 = fmaf(qz, wzr[0], fmaf(qy, wyr[0], fmaf(qx, wxr[0], bbr[0])));
            float v1 = fmaf(qz, wzr[1], fmaf(qy, wyr[1], fmaf(qx, wxr[1], bbr[1])));
            float v2 = fmaf(qz, wzr[2], fmaf(qy, wyr[2], fmaf(qx, wxr[2], bbr[2])));
            float v3 = fmaf(qz, wzr[3], fmaf(qy, wyr[3], fmaf(qx, wxr[3], bbr[3])));
            v0 = fmaxf(v0, 0.f); v1 = fmaxf(v1, 0.f);
            v2 = fmaxf(v2, 0.f); v3 = fmaxf(v3, 0.f);
            __hip_bfloat162 lo = __float22bfloat162_rn(float2{v0, v1});
            __hip_bfloat162 hi = __float22bfloat162_rn(float2{v2, v3});
            uint2 val;
            val.x = *(uint32_t*)&lo;
            val.y = *(uint32_t*)&hi;
            int idx = (row*64 + 4*dg) ^ ((row & 7) << 3);
            *(uint2*)&h1b[idx] = val;            // ds_write_b64
        }
        __syncthreads();

        #pragma unroll
        for (int mt = 0; mt < 4; mt++) {
            int r = mt*16 + l15;
            int ai0 = (r*64 +      kb) ^ ((r & 7) << 3);
            int ai1 = (r*64 + 32 + kb) ^ ((r & 7) << 3);
            bf16x8 a0 = *(const bf16x8*)&h1b[ai0];
            bf16x8 a1 = *(const bf16x8*)&h1b[ai1];
            f32x4 z = {0.f, 0.f, 0.f, 0.f};
            f32x4 c;
            c = __builtin_amdgcn_mfma_f32_16x16x32_bf16(a0, b00, z, 0, 0, 0);
            c = __builtin_amdgcn_mfma_f32_16x16x32_bf16(a1, b01, c, 0, 0, 0);
            gm0 = fmaxf(gm0, fmaxf(fmaxf(c[0], c[1]), fmaxf(c[2], c[3])));
            c = __builtin_amdgcn_mfma_f32_16x16x32_bf16(a0, b10, z, 0, 0, 0);
            c = __builtin_amdgcn_mfma_f32_16x16x32_bf16(a1, b11, c, 0, 0, 0);
            gm1 = fmaxf(gm1, fmaxf(fmaxf(c[0], c[1]), fmaxf(c[2], c[3])));
        }
        __syncthreads();   // before next chunk overwrites h1b
    }

    // reduce across the 4 row-groups (lanes L, L^16, L^32, L^48 share col)
    gm0 = fmaxf(gm0, __shfl_xor(gm0, 16)); gm0 = fmaxf(gm0, __shfl_xor(gm0, 32));
    gm1 = fmaxf(gm1, __shfl_xor(gm1, 16)); gm1 = fmaxf(gm1, __shfl_xor(gm1, 32));
    if (lane < 16) {
        gmax2[wv*16     + lane] = gm0;
        gmax2[(wv+4)*16 + lane] = gm1;
    }
    __syncthreads();
    if (tid < 128) gmax2[tid] = fmaxf(gmax2[tid] + b2[tid], 0.f);   // bias + relu
    __syncthreads();

    // final heads: out = [g@Wc+bc, g@Wr+br]
    if (tid < 5) {
        const float* Wv; float bias; int stride;
        if (tid == 0) { Wv = Wc;            bias = bc[0];      stride = 1; }
        else          { Wv = Wr + (tid-1);  bias = br[tid-1];  stride = 4; }
        float acc = bias;
        for (int i = 0; i < 128; i++) acc = fmaf(gmax2[i], Wv[i*stride], acc);
        out[5*a + tid] = acc;
    }
}

// ---------------- launch ----------------

extern "C" void kernel_launch(void* const* d_in, const int* in_sizes, int n_in,
                              void* d_out, int out_size, void* d_ws, size_t ws_size,
                              hipStream_t stream) {
    const float* pts  = (const float*)d_in[0];
    const float* anch = (const float*)d_in[1];
    const float* W1   = (const float*)d_in[2];
    const float* b1   = (const float*)d_in[3];
    const float* W2   = (const float*)d_in[4];
    const float* b2   = (const float*)d_in[5];
    const float* Wc   = (const float*)d_in[6];
    const float* bc   = (const float*)d_in[7];
    const float* Wr   = (const float*)d_in[8];
    const float* br   = (const float*)d_in[9];
    float* out = (float*)d_out;

    char* ws = (char*)d_ws;
    float4*         binned = (float4*)ws;                     // NCELL*CAP float4 = 3.84 MB @0
    int*            gcount = (int*)(ws + (size_t)NCELL*CAP*16);   // 625 ints
    unsigned short* w2tg   = (unsigned short*)(ws + (size_t)NCELL*CAP*16 + 4096); // 16 KB

    hipMemsetAsync(gcount, 0, NCELL*4, stream);
    k_bin  <<<HB, 256, 0, stream>>>(pts, W2, gcount, binned, w2tg);
    k_main <<<NANCH, 256, 0, stream>>>(pts, anch, W1, b1, b2, Wc, bc, Wr, br,
                                       w2tg, binned, gcount, out);
}